// Round 1
// baseline (1410.639 us; speedup 1.0000x reference)
//
#include <hip/hip_runtime.h>
#include <stdint.h>

// Problem constants
#define B_SZ 2048
#define N_SZ 512
#define H_SZ 20
#define T_STEPS 3

typedef unsigned short u16;
typedef __attribute__((ext_vector_type(8))) short bf8;   // 8 bf16 (4 VGPRs)
typedef __attribute__((ext_vector_type(4))) float f4;    // MFMA 16x16 accumulator

#define MFMA(a, b, c) __builtin_amdgcn_mfma_f32_16x16x32_bf16((a), (b), (c), 0, 0, 0)

__device__ __forceinline__ u16 f2bf(float f) {
    union { float f; uint32_t u; } v; v.f = f;
    uint32_t u = v.u;
    u += 0x7FFFu + ((u >> 16) & 1u);   // RNE
    return (u16)(u >> 16);
}
__device__ __forceinline__ float bf2f(u16 h) {
    union { uint32_t u; float f; } v; v.u = ((uint32_t)h) << 16;
    return v.f;
}
__device__ __forceinline__ uint32_t pk2(float a, float b) {
    return (uint32_t)f2bf(a) | ((uint32_t)f2bf(b) << 16);
}
__device__ __forceinline__ uint2 pack4(f4 v) {
    uint2 r; r.x = pk2(v[0], v[1]); r.y = pk2(v[2], v[3]); return r;
}
// scratch2 addressing: [c (16 cols)][fblock^swizzle (8)][8], bf16 elements
__device__ __forceinline__ int scoff(int c, int f) {
    return c * 64 + (((f >> 3) ^ (c & 7)) << 3) + (f & 7);
}
__device__ __forceinline__ float sigm(float x) { return 1.f / (1.f + __expf(-x)); }

// ---------------- prep kernels ----------------

// x [B][N][H] f32  ->  nodes [B][H][N] bf16   (one block per batch)
__global__ void prep_nodes(const float* __restrict__ x, u16* __restrict__ nodes) {
    __shared__ float xt[N_SZ * H_SZ];
    int b = blockIdx.x;
    const float* xb = x + (size_t)b * N_SZ * H_SZ;
    for (int i = threadIdx.x; i < N_SZ * H_SZ; i += 256) xt[i] = xb[i];
    __syncthreads();
    u16* nb = nodes + (size_t)b * H_SZ * N_SZ;
    for (int i = threadIdx.x; i < H_SZ * N_SZ; i += 256) {
        int h = i / N_SZ, m = i - h * N_SZ;
        nb[i] = f2bf(xt[m * H_SZ + h]);
    }
}

// xo [B][N][H] bf16 = x @ W_out[:,H:].T + b_out  (thread per (b,n))
__global__ void prep_xo(const float* __restrict__ x, const float* __restrict__ Wout,
                        const float* __restrict__ bout, u16* __restrict__ xo) {
    int i = blockIdx.x * 256 + threadIdx.x;      // (b*N+n)
    const float* xv = x + (size_t)i * H_SZ;
    float xl[H_SZ];
    #pragma unroll
    for (int h = 0; h < H_SZ; h++) xl[h] = xv[h];
    u16* o = xo + (size_t)i * H_SZ;
    for (int hp = 0; hp < H_SZ; hp++) {
        float s = bout[hp];
        const float* wr = Wout + hp * 2 * H_SZ + H_SZ;
        #pragma unroll
        for (int h = 0; h < H_SZ; h++) s += xl[h] * wr[h];
        o[hp] = f2bf(s);
    }
}

// A fragment tables: pAT[nt][kt][lane][8] = A[n][m] (B-op for agg_in),
//                    pA [nt][kt][lane][8] = A[m][n] (B-op for agg_out)
__global__ void prep_afrag(const float* __restrict__ A, u16* __restrict__ pAT,
                           u16* __restrict__ pA) {
    int idx = blockIdx.x * 256 + threadIdx.x;    // (nt*16 + kt)*64 + lane
    int lane = idx & 63;
    int kt = (idx >> 6) & 15;
    int nt = idx >> 10;
    int n = nt * 16 + (lane & 15);
    int k0 = kt * 32 + (lane >> 4) * 8;
    u16* d1 = pAT + (size_t)idx * 8;
    u16* d2 = pA + (size_t)idx * 8;
    #pragma unroll
    for (int j = 0; j < 8; j++) {
        int m = k0 + j;
        d1[j] = f2bf(A[(size_t)n * N_SZ + m]);
        d2[j] = f2bf(A[(size_t)m * N_SZ + n]);
    }
}

// Gate weight fragment tables.
// wbig: M=96 (rows 0-19 z | 32-51 r | 64-83 h-av; zero pad), K=64
//       (k 0-39: W*w over [agg_in,agg_out]; k 40-59: W*u over fn (zero for h); 60-63 zero)
// whu : M=32 K=32 : W5u zero-padded
// wo1 : M=32 K=32 : W_out[:, :H] zero-padded
__global__ void prep_wfrag(const float* __restrict__ W3w, const float* __restrict__ W3u,
                           const float* __restrict__ W4w, const float* __restrict__ W4u,
                           const float* __restrict__ W5w, const float* __restrict__ W5u,
                           const float* __restrict__ Wout,
                           u16* __restrict__ wbig, u16* __restrict__ whu, u16* __restrict__ wo1) {
    int t = blockIdx.x * 256 + threadIdx.x;      // 0..1023
    int lane = t & 63;
    int l16 = lane & 15, quad = lane >> 4;
    if (t < 768) {
        int kt = (t >> 6) & 1;
        int mt = t >> 7;
        int mrow = mt * 16 + l16;
        int g = mrow >> 5, lr = mrow & 31;
        u16* d = wbig + (size_t)t * 8;
        #pragma unroll
        for (int j = 0; j < 8; j++) {
            int k = kt * 32 + quad * 8 + j;
            float v = 0.f;
            if (lr < 20) {
                if (k < 40) {
                    const float* W = (g == 0) ? W3w : (g == 1) ? W4w : W5w;
                    v = W[lr * 40 + k];
                } else if (k < 60 && g < 2) {
                    const float* U = (g == 0) ? W3u : W4u;
                    v = U[lr * 20 + (k - 40)];
                }
            }
            d[j] = f2bf(v);
        }
    } else if (t < 896) {
        int tt = t - 768;
        int mrow = (tt >> 6) * 16 + l16;
        u16* d = whu + (size_t)tt * 8;
        #pragma unroll
        for (int j = 0; j < 8; j++) {
            int k = quad * 8 + j;
            d[j] = f2bf((mrow < 20 && k < 20) ? W5u[mrow * 20 + k] : 0.f);
        }
    } else {
        int tt = t - 896;
        int mrow = (tt >> 6) * 16 + l16;
        u16* d = wo1 + (size_t)tt * 8;
        #pragma unroll
        for (int j = 0; j < 8; j++) {
            int k = quad * 8 + j;
            d[j] = f2bf((mrow < 20 && k < 20) ? Wout[mrow * 40 + k] : 0.f);
        }
    }
}

__global__ void ws_too_small(float* out) { out[0] = 12345.0f; }

// ---------------- per-step fused kernel ----------------
// One workgroup = 2 batches. LDS: Xs[40 rows (b,h)][512 m] bf16 XOR-swizzled
// + per-wave scratch2 (16 cols x 64 feats, swizzled). 49152 B -> 3 blocks/CU.
__global__ __launch_bounds__(256, 3)
void step_kernel(const u16* __restrict__ pAT, const u16* __restrict__ pA,
                 const u16* __restrict__ wbig, const u16* __restrict__ whu,
                 const u16* __restrict__ wo1, const u16* __restrict__ xo,
                 u16* __restrict__ nodes, float* __restrict__ out, int t_step)
{
    __shared__ __align__(16) u16 lds_all[40 * 512 + 4 * 1024];   // Xs | sc2, 49152 B
    u16* Xs = lds_all;
    int tid = threadIdx.x;
    int wv = tid >> 6, lane = tid & 63;
    int l16 = lane & 15, quad = lane >> 4;
    int b0 = blockIdx.x * 2;
    u16* scw = lds_all + 40 * 512 + wv * 1024;

    // ---- phase 1: stage nodes[b0..b0+1] -> Xs (swizzled) ----
    const u16* nb = nodes + (size_t)b0 * (H_SZ * N_SZ);
    #pragma unroll
    for (int i = 0; i < 10; i++) {
        int blk = i * 256 + tid;           // 0..2559 : row(40) x mblk(64)
        int row = blk >> 6, mblk = blk & 63;
        uint4 v = *(const uint4*)(nb + (size_t)row * 512 + mblk * 8);
        *(uint4*)&Xs[row * 512 + ((mblk ^ (row & 7)) << 3)] = v;
    }
    __syncthreads();
    // From here waves are fully independent (own n-tiles, own scratch).

    for (int p = 0; p < 4; p++) {
        int nt0 = wv * 8 + p * 2;

        // ---- phase 2: aggregation GEMM for an n-tile pair ----
        f4 acc[2][3][2];                    // [ntL][mt][agg]
        #pragma unroll
        for (int a0 = 0; a0 < 2; a0++)
            #pragma unroll
            for (int a1 = 0; a1 < 3; a1++)
                #pragma unroll
                for (int a2 = 0; a2 < 2; a2++)
                    acc[a0][a1][a2] = (f4){0.f, 0.f, 0.f, 0.f};

        for (int kt = 0; kt < 16; kt++) {
            bf8 af[3];
            #pragma unroll
            for (int mt = 0; mt < 3; mt++) {
                int row = mt * 16 + l16;                       // rows 40-47 read junk; C rows ignored
                int kb = (kt * 4 + quad) ^ (row & 7);
                af[mt] = *(const bf8*)&Xs[row * 512 + kb * 8];
            }
            #pragma unroll
            for (int ntL = 0; ntL < 2; ntL++) {
                size_t fo = ((size_t)((nt0 + ntL) * 16 + kt) * 64 + lane) * 8;
                bf8 bi = *(const bf8*)(pAT + fo);
                bf8 bo = *(const bf8*)(pA + fo);
                #pragma unroll
                for (int mt = 0; mt < 3; mt++) {
                    acc[ntL][mt][0] = MFMA(af[mt], bi, acc[ntL][mt][0]);
                    acc[ntL][mt][1] = MFMA(af[mt], bo, acc[ntL][mt][1]);
                }
            }
        }

        // ---- phase 3: gates + update + output, per (n-tile, batch) pass ----
        #pragma unroll
        for (int ntL = 0; ntL < 2; ntL++) {
            int nt = nt0 + ntL;
            int nglob = nt * 16 + l16;

            #pragma unroll
            for (int bs = 0; bs < 2; bs++) {
                // 3a: agg C-tiles (rows of this batch) -> scratch feats 0..39
                //     (f = agg*20+h, c = n_local). Packed b64 writes.
                #pragma unroll
                for (int mt = 0; mt < 3; mt++) {
                    int row0 = mt * 16 + quad * 4;               // 4-aligned; 20-boundary safe
                    int bsof = (row0 >= 20) ? 1 : 0;
                    int h0 = row0 - bsof * 20;
                    if (row0 < 40 && bsof == bs) {
                        *(uint2*)&scw[scoff(l16, h0)]      = pack4(acc[ntL][mt][0]);
                        *(uint2*)&scw[scoff(l16, 20 + h0)] = pack4(acc[ntL][mt][1]);
                    }
                }
                // 3a2: fn -> feats 40..59 (this batch); zero feats 60..63
                {
                    int c = l16;
                    int m = nt * 16 + c;
                    int mb = m >> 3, mo = m & 7;
                    int h0f = quad * 5;
                    #pragma unroll
                    for (int i = 0; i < 5; i++) {
                        int h = h0f + i;
                        int row = bs * 20 + h;
                        scw[scoff(c, 40 + h)] = Xs[row * 512 + ((mb ^ (row & 7)) << 3) + mo];
                    }
                    scw[scoff(c, 60 + quad)] = 0;
                }

                // 3b: G1 = Wbig(96x64) @ scratch2(64x16): z|r|h_av pre-activations
                f4 g1[6];
                #pragma unroll
                for (int a0 = 0; a0 < 6; a0++) g1[a0] = (f4){0.f, 0.f, 0.f, 0.f};
                #pragma unroll
                for (int kt = 0; kt < 2; kt++) {
                    int fb = (kt * 4 + quad) ^ (l16 & 7);
                    bf8 bfr = *(const bf8*)&scw[l16 * 64 + fb * 8];
                    #pragma unroll
                    for (int mt = 0; mt < 6; mt++) {
                        bf8 wf = *(const bf8*)(wbig + ((size_t)(mt * 2 + kt) * 64 + lane) * 8);
                        g1[mt] = MFMA(wf, bfr, g1[mt]);
                    }
                }

                // 3c: rp = sigmoid(r)*fn -> feats 0..19 (agg_in slots are dead)
                {
                    int c = l16;
                    uint2 fl = *(const uint2*)&scw[scoff(c, 40 + quad * 4)];
                    uint2 rp;
                    rp.x = pk2(sigm(g1[2][0]) * bf2f((u16)fl.x),
                               sigm(g1[2][1]) * bf2f((u16)(fl.x >> 16)));
                    rp.y = pk2(sigm(g1[2][2]) * bf2f((u16)fl.y),
                               sigm(g1[2][3]) * bf2f((u16)(fl.y >> 16)));
                    *(uint2*)&scw[scoff(c, quad * 4)] = rp;
                    if (quad == 0) {
                        uint2 fl2 = *(const uint2*)&scw[scoff(c, 56)];
                        uint2 rp2;
                        rp2.x = pk2(sigm(g1[3][0]) * bf2f((u16)fl2.x),
                                    sigm(g1[3][1]) * bf2f((u16)(fl2.x >> 16)));
                        rp2.y = pk2(sigm(g1[3][2]) * bf2f((u16)fl2.y),
                                    sigm(g1[3][3]) * bf2f((u16)(fl2.y >> 16)));
                        *(uint2*)&scw[scoff(c, 16)] = rp2;
                    }
                }

                // 3d: hu = W5u_pad(32x32) @ rp
                f4 hu[2];
                hu[0] = (f4){0.f, 0.f, 0.f, 0.f};
                hu[1] = (f4){0.f, 0.f, 0.f, 0.f};
                {
                    int fb = quad ^ (l16 & 7);
                    bf8 bfr = *(const bf8*)&scw[l16 * 64 + fb * 8];
                    #pragma unroll
                    for (int mt = 0; mt < 2; mt++) {
                        bf8 wf = *(const bf8*)(whu + ((size_t)(mt * 64) + lane) * 8);
                        hu[mt] = MFMA(wf, bfr, hu[mt]);
                    }
                }

                // 3e: fn_new = (1-z)*fn + z*tanh(h_av + hu); write nodes + feats 0..19
                {
                    int c = l16;
                    size_t nbase = ((size_t)(b0 + bs) * H_SZ) * N_SZ + nglob;
                    uint2 fl = *(const uint2*)&scw[scoff(c, 40 + quad * 4)];
                    u16 fnl[4] = {(u16)fl.x, (u16)(fl.x >> 16), (u16)fl.y, (u16)(fl.y >> 16)};
                    u16 wv4[4];
                    #pragma unroll
                    for (int r = 0; r < 4; r++) {
                        int hp = quad * 4 + r;
                        float fn = bf2f(fnl[r]);
                        float z = sigm(g1[0][r]);
                        float hpre = g1[4][r] + hu[0][r];
                        float hv = 2.f / (1.f + __expf(-2.f * hpre)) - 1.f;
                        u16 w = f2bf((1.f - z) * fn + z * hv);
                        nodes[nbase + (size_t)hp * N_SZ] = w;
                        wv4[r] = w;
                    }
                    uint2 wp;
                    wp.x = (uint32_t)wv4[0] | ((uint32_t)wv4[1] << 16);
                    wp.y = (uint32_t)wv4[2] | ((uint32_t)wv4[3] << 16);
                    *(uint2*)&scw[scoff(c, quad * 4)] = wp;
                    if (quad == 0) {
                        uint2 fl2 = *(const uint2*)&scw[scoff(c, 56)];
                        u16 fnl2[4] = {(u16)fl2.x, (u16)(fl2.x >> 16), (u16)fl2.y, (u16)(fl2.y >> 16)};
                        u16 wv42[4];
                        #pragma unroll
                        for (int r = 0; r < 4; r++) {
                            int hp = 16 + r;
                            float fn = bf2f(fnl2[r]);
                            float z = sigm(g1[1][r]);
                            float hpre = g1[5][r] + hu[1][r];
                            float hv = 2.f / (1.f + __expf(-2.f * hpre)) - 1.f;
                            u16 w = f2bf((1.f - z) * fn + z * hv);
                            nodes[nbase + (size_t)hp * N_SZ] = w;
                            wv42[r] = w;
                        }
                        uint2 wp2;
                        wp2.x = (uint32_t)wv42[0] | ((uint32_t)wv42[1] << 16);
                        wp2.y = (uint32_t)wv42[2] | ((uint32_t)wv42[3] << 16);
                        *(uint2*)&scw[scoff(c, 16)] = wp2;
                    }
                }

                // 3f: og = Wo1_pad(32x32) @ fn_new
                f4 og[2];
                og[0] = (f4){0.f, 0.f, 0.f, 0.f};
                og[1] = (f4){0.f, 0.f, 0.f, 0.f};
                {
                    int fb = quad ^ (l16 & 7);
                    bf8 bfr = *(const bf8*)&scw[l16 * 64 + fb * 8];
                    #pragma unroll
                    for (int mt = 0; mt < 2; mt++) {
                        bf8 wf = *(const bf8*)(wo1 + ((size_t)(mt * 64) + lane) * 8);
                        og[mt] = MFMA(wf, bfr, og[mt]);
                    }
                }

                // 3g: out = og + xo, vectorized xo (uint2) + float4 stores
                {
                    int bg = b0 + bs;
                    size_t xob = ((size_t)bg * N_SZ + nglob) * H_SZ;
                    size_t ob = (((size_t)t_step * B_SZ + bg) * N_SZ + nglob) * H_SZ;
                    {
                        uint2 xp = *(const uint2*)(xo + xob + quad * 4);
                        u16 xl[4] = {(u16)xp.x, (u16)(xp.x >> 16), (u16)xp.y, (u16)(xp.y >> 16)};
                        f4 v;
                        #pragma unroll
                        for (int r = 0; r < 4; r++) v[r] = og[0][r] + bf2f(xl[r]);
                        *(f4*)(out + ob + quad * 4) = v;
                    }
                    if (quad == 0) {
                        uint2 xp = *(const uint2*)(xo + xob + 16);
                        u16 xl[4] = {(u16)xp.x, (u16)(xp.x >> 16), (u16)xp.y, (u16)(xp.y >> 16)};
                        f4 v;
                        #pragma unroll
                        for (int r = 0; r < 4; r++) v[r] = og[1][r] + bf2f(xl[r]);
                        *(f4*)(out + ob + 16) = v;
                    }
                }
            }
        }
    }
}

// ---------------- host ----------------
#define WS_NODES   0
#define WS_XO      41943040UL
#define WS_PAT     83886080UL
#define WS_PA      84410368UL
#define WS_WBIG    84934656UL
#define WS_WHU     84946944UL
#define WS_WO1     84948992UL
#define WS_NEEDED  84951040UL

extern "C" void kernel_launch(void* const* d_in, const int* in_sizes, int n_in,
                              void* d_out, int out_size, void* d_ws, size_t ws_size,
                              hipStream_t stream) {
    const float* x    = (const float*)d_in[0];
    const float* A    = (const float*)d_in[1];
    const float* W3w  = (const float*)d_in[2];
    const float* W3u  = (const float*)d_in[3];
    const float* W4w  = (const float*)d_in[4];
    const float* W4u  = (const float*)d_in[5];
    const float* W5w  = (const float*)d_in[6];
    const float* W5u  = (const float*)d_in[7];
    const float* Wout = (const float*)d_in[8];
    const float* bout = (const float*)d_in[9];
    float* out = (float*)d_out;

    if (ws_size < WS_NEEDED) {           // unambiguous failure signature
        ws_too_small<<<1, 1, 0, stream>>>(out);
        return;
    }
    char* ws = (char*)d_ws;
    u16* nodes = (u16*)(ws + WS_NODES);
    u16* xo    = (u16*)(ws + WS_XO);
    u16* pAT   = (u16*)(ws + WS_PAT);
    u16* pA    = (u16*)(ws + WS_PA);
    u16* wbig  = (u16*)(ws + WS_WBIG);
    u16* whu   = (u16*)(ws + WS_WHU);
    u16* wo1   = (u16*)(ws + WS_WO1);

    prep_nodes<<<B_SZ, 256, 0, stream>>>(x, nodes);
    prep_xo<<<(B_SZ * N_SZ) / 256, 256, 0, stream>>>(x, Wout, bout, xo);
    prep_afrag<<<128, 256, 0, stream>>>(A, pAT, pA);
    prep_wfrag<<<4, 256, 0, stream>>>(W3w, W3u, W4w, W4u, W5w, W5u, Wout, wbig, whu, wo1);

    for (int t = 0; t < T_STEPS; t++)
        step_kernel<<<B_SZ / 2, 256, 0, stream>>>(pAT, pA, wbig, whu, wo1, xo, nodes, out, t);
}

// Round 2
// 1361.920 us; speedup vs baseline: 1.0358x; 1.0358x over previous
//
#include <hip/hip_runtime.h>
#include <stdint.h>

// Problem constants
#define B_SZ 2048
#define N_SZ 512
#define H_SZ 20
#define T_STEPS 3

typedef unsigned short u16;
typedef __attribute__((ext_vector_type(8))) short bf8;   // 8 bf16 (4 VGPRs)
typedef __attribute__((ext_vector_type(4))) float f4;    // MFMA 16x16 accumulator

#define MFMA(a, b, c) __builtin_amdgcn_mfma_f32_16x16x32_bf16((a), (b), (c), 0, 0, 0)

__device__ __forceinline__ u16 f2bf(float f) {
    union { float f; uint32_t u; } v; v.f = f;
    uint32_t u = v.u;
    u += 0x7FFFu + ((u >> 16) & 1u);   // RNE
    return (u16)(u >> 16);
}
__device__ __forceinline__ float bf2f(u16 h) {
    union { uint32_t u; float f; } v; v.u = ((uint32_t)h) << 16;
    return v.f;
}
// scratch2 addressing: [c (32 cols)][fblock^swizzle (8)][8], bf16 elements
__device__ __forceinline__ int scoff(int c, int f) {
    return c * 64 + (((f >> 3) ^ (c & 7)) << 3) + (f & 7);
}
__device__ __forceinline__ float sigm(float x) { return 1.f / (1.f + __expf(-x)); }

// ---------------- prep kernels ----------------

// x [B][N][H] f32  ->  nodes [B][H][N] bf16   (one block per batch)
__global__ void prep_nodes(const float* __restrict__ x, u16* __restrict__ nodes) {
    __shared__ float xt[N_SZ * H_SZ];
    int b = blockIdx.x;
    const float* xb = x + (size_t)b * N_SZ * H_SZ;
    for (int i = threadIdx.x; i < N_SZ * H_SZ; i += 256) xt[i] = xb[i];
    __syncthreads();
    u16* nb = nodes + (size_t)b * H_SZ * N_SZ;
    for (int i = threadIdx.x; i < H_SZ * N_SZ; i += 256) {
        int h = i / N_SZ, m = i - h * N_SZ;
        nb[i] = f2bf(xt[m * H_SZ + h]);
    }
}

// xo [B][N][H] bf16 = x @ W_out[:,H:].T + b_out  (thread per (b,n))
__global__ void prep_xo(const float* __restrict__ x, const float* __restrict__ Wout,
                        const float* __restrict__ bout, u16* __restrict__ xo) {
    int i = blockIdx.x * 256 + threadIdx.x;      // (b*N+n)
    const float* xv = x + (size_t)i * H_SZ;
    float xl[H_SZ];
    #pragma unroll
    for (int h = 0; h < H_SZ; h++) xl[h] = xv[h];
    u16* o = xo + (size_t)i * H_SZ;
    for (int hp = 0; hp < H_SZ; hp++) {
        float s = bout[hp];
        const float* wr = Wout + hp * 2 * H_SZ + H_SZ;
        #pragma unroll
        for (int h = 0; h < H_SZ; h++) s += xl[h] * wr[h];
        o[hp] = f2bf(s);
    }
}

// A fragment tables: pAT[nt][kt][lane][8] = A[n][m] (B-op for agg_in),
//                    pA [nt][kt][lane][8] = A[m][n] (B-op for agg_out)
__global__ void prep_afrag(const float* __restrict__ A, u16* __restrict__ pAT,
                           u16* __restrict__ pA) {
    int idx = blockIdx.x * 256 + threadIdx.x;    // (nt*16 + kt)*64 + lane
    int lane = idx & 63;
    int kt = (idx >> 6) & 15;
    int nt = idx >> 10;
    int n = nt * 16 + (lane & 15);
    int k0 = kt * 32 + (lane >> 4) * 8;
    u16* d1 = pAT + (size_t)idx * 8;
    u16* d2 = pA + (size_t)idx * 8;
    #pragma unroll
    for (int j = 0; j < 8; j++) {
        int m = k0 + j;
        d1[j] = f2bf(A[(size_t)n * N_SZ + m]);
        d2[j] = f2bf(A[(size_t)m * N_SZ + n]);
    }
}

// Gate weight fragment tables.
// wbig: M=96 (rows 0-19 z | 32-51 r | 64-83 h-av; zero pad), K=64
//       (k 0-39: W*w over [agg_in,agg_out]; k 40-59: W*u over fn (zero for h); 60-63 zero)
// whu : M=32 K=32 : W5u zero-padded
// wo1 : M=32 K=32 : W_out[:, :H] zero-padded
__global__ void prep_wfrag(const float* __restrict__ W3w, const float* __restrict__ W3u,
                           const float* __restrict__ W4w, const float* __restrict__ W4u,
                           const float* __restrict__ W5w, const float* __restrict__ W5u,
                           const float* __restrict__ Wout,
                           u16* __restrict__ wbig, u16* __restrict__ whu, u16* __restrict__ wo1) {
    int t = blockIdx.x * 256 + threadIdx.x;      // 0..1023
    int lane = t & 63;
    int l16 = lane & 15, quad = lane >> 4;
    if (t < 768) {
        int kt = (t >> 6) & 1;
        int mt = t >> 7;
        int mrow = mt * 16 + l16;
        int g = mrow >> 5, lr = mrow & 31;
        u16* d = wbig + (size_t)t * 8;
        #pragma unroll
        for (int j = 0; j < 8; j++) {
            int k = kt * 32 + quad * 8 + j;
            float v = 0.f;
            if (lr < 20) {
                if (k < 40) {
                    const float* W = (g == 0) ? W3w : (g == 1) ? W4w : W5w;
                    v = W[lr * 40 + k];
                } else if (k < 60 && g < 2) {
                    const float* U = (g == 0) ? W3u : W4u;
                    v = U[lr * 20 + (k - 40)];
                }
            }
            d[j] = f2bf(v);
        }
    } else if (t < 896) {
        int tt = t - 768;
        int mrow = (tt >> 6) * 16 + l16;
        u16* d = whu + (size_t)tt * 8;
        #pragma unroll
        for (int j = 0; j < 8; j++) {
            int k = quad * 8 + j;
            d[j] = f2bf((mrow < 20 && k < 20) ? W5u[mrow * 20 + k] : 0.f);
        }
    } else {
        int tt = t - 896;
        int mrow = (tt >> 6) * 16 + l16;
        u16* d = wo1 + (size_t)tt * 8;
        #pragma unroll
        for (int j = 0; j < 8; j++) {
            int k = quad * 8 + j;
            d[j] = f2bf((mrow < 20 && k < 20) ? Wout[mrow * 40 + k] : 0.f);
        }
    }
}

__global__ void ws_too_small(float* out) { out[0] = 12345.0f; }

// ---------------- per-step fused kernel ----------------
// One workgroup = 2 batches, 8 waves. LDS: Xs[40 rows (b,h)][512 m] bf16
// XOR-swizzled + per-wave scratch2 (32 cols x 64 feats, swizzled).
// 73728 B -> 2 blocks/CU -> 16 waves/CU (vs 8 in the 256-thread version).
// VGPR must stay <=128 for 4 waves/SIMD: __launch_bounds__(512, 4) pins it.
__global__ __launch_bounds__(512, 4)
void step_kernel(const u16* __restrict__ pAT, const u16* __restrict__ pA,
                 const u16* __restrict__ wbig, const u16* __restrict__ whu,
                 const u16* __restrict__ wo1, const u16* __restrict__ xo,
                 u16* __restrict__ nodes, float* __restrict__ out, int t_step)
{
    __shared__ __align__(16) u16 lds_all[40 * 512 + 8 * 2048];   // Xs | sc2, 73728 B
    u16* Xs = lds_all;
    int tid = threadIdx.x;
    int wv = tid >> 6, lane = tid & 63;
    int l16 = lane & 15, quad = lane >> 4;
    int b0 = blockIdx.x * 2;
    u16* scw = lds_all + 40 * 512 + wv * 2048;

    // ---- phase 1: stage nodes[b0..b0+1] -> Xs (swizzled) ----
    const u16* nb = nodes + (size_t)b0 * (H_SZ * N_SZ);
    #pragma unroll
    for (int i = 0; i < 5; i++) {
        int blk = i * 512 + tid;           // 0..2559 : row(40) x mblk(64)
        int row = blk >> 6, mblk = blk & 63;
        uint4 v = *(const uint4*)(nb + (size_t)row * 512 + mblk * 8);
        *(uint4*)&Xs[row * 512 + ((mblk ^ (row & 7)) << 3)] = v;
    }
    __syncthreads();
    // From here waves are fully independent (own n-tiles, own scratch).

    for (int p = 0; p < 2; p++) {
        int nt0 = wv * 4 + p * 2;

        // ---- phase 2: aggregation GEMM for an n-tile pair ----
        f4 acc[2][3][2];                    // [ntL][mt][agg]
        #pragma unroll
        for (int a0 = 0; a0 < 2; a0++)
            #pragma unroll
            for (int a1 = 0; a1 < 3; a1++)
                #pragma unroll
                for (int a2 = 0; a2 < 2; a2++)
                    acc[a0][a1][a2] = (f4){0.f, 0.f, 0.f, 0.f};

        for (int kt = 0; kt < 16; kt++) {
            bf8 af[3];
            #pragma unroll
            for (int mt = 0; mt < 3; mt++) {
                int row = mt * 16 + l16;                       // rows 40-47 read junk; C rows ignored
                int kb = (kt * 4 + quad) ^ (row & 7);
                af[mt] = *(const bf8*)&Xs[row * 512 + kb * 8];
            }
            #pragma unroll
            for (int ntL = 0; ntL < 2; ntL++) {
                size_t fo = ((size_t)((nt0 + ntL) * 16 + kt) * 64 + lane) * 8;
                bf8 bi = *(const bf8*)(pAT + fo);
                bf8 bo = *(const bf8*)(pA + fo);
                #pragma unroll
                for (int mt = 0; mt < 3; mt++) {
                    acc[ntL][mt][0] = MFMA(af[mt], bi, acc[ntL][mt][0]);
                    acc[ntL][mt][1] = MFMA(af[mt], bo, acc[ntL][mt][1]);
                }
            }
        }

        // ---- phase 3: gates + update + output, per n-tile ----
        #pragma unroll
        for (int ntL = 0; ntL < 2; ntL++) {
            int nt = nt0 + ntL;
            int nglob = nt * 16 + l16;

            // 3a: agg C-tiles -> scratch2 feats 0..39 (f = agg*20+h, c = bsub*16+n_local)
            #pragma unroll
            for (int mt = 0; mt < 3; mt++) {
                if (mt < 2 || quad < 2) {
                    int row0 = mt * 16 + quad * 4;              // 4-aligned; 20-boundary safe
                    int bs = (row0 >= 20) ? 1 : 0;
                    int h0 = row0 - bs * 20;
                    int c = bs * 16 + l16;
                    #pragma unroll
                    for (int r = 0; r < 4; r++) {
                        scw[scoff(c, h0 + r)]      = f2bf(acc[ntL][mt][0][r]);
                        scw[scoff(c, 20 + h0 + r)] = f2bf(acc[ntL][mt][1][r]);
                    }
                }
            }
            // 3a2: fn -> feats 40..59 ; zero feats 60..63 (avoid NaN garbage into MFMA)
            {
                int c = lane & 31;
                int h0 = (lane >> 5) * 10;
                int bs = c >> 4, nl = c & 15;
                int m = nt * 16 + nl;
                int mb = m >> 3, mo = m & 7;
                #pragma unroll
                for (int i = 0; i < 10; i++) {
                    int h = h0 + i;
                    int row = bs * 20 + h;
                    u16 v = Xs[row * 512 + ((mb ^ (row & 7)) << 3) + mo];
                    scw[scoff(c, 40 + h)] = v;
                }
                if (lane < 32) {
                    #pragma unroll
                    for (int f = 60; f < 64; f++) scw[scoff(c, f)] = 0;
                }
            }

            // 3b: G1 = Wbig(96x64) @ scratch2(64x32): z|r|h_av pre-activations
            f4 g1[6][2];
            #pragma unroll
            for (int a0 = 0; a0 < 6; a0++) { g1[a0][0] = (f4){0,0,0,0}; g1[a0][1] = (f4){0,0,0,0}; }
            #pragma unroll
            for (int kt = 0; kt < 2; kt++) {
                bf8 bfr[2];
                #pragma unroll
                for (int ct = 0; ct < 2; ct++) {
                    int c = ct * 16 + l16;
                    int fb = (kt * 4 + quad) ^ (c & 7);
                    bfr[ct] = *(const bf8*)&scw[c * 64 + fb * 8];
                }
                #pragma unroll
                for (int mt = 0; mt < 6; mt++) {
                    bf8 wf = *(const bf8*)(wbig + ((size_t)(mt * 2 + kt) * 64 + lane) * 8);
                    g1[mt][0] = MFMA(wf, bfr[0], g1[mt][0]);
                    g1[mt][1] = MFMA(wf, bfr[1], g1[mt][1]);
                }
            }

            // 3c: rp = sigmoid(r)*fn -> feats 0..19 (agg_in slots are dead)
            #pragma unroll
            for (int ct = 0; ct < 2; ct++) {
                int c = ct * 16 + l16;
                #pragma unroll
                for (int r = 0; r < 4; r++) {
                    int hp = quad * 4 + r;
                    float fn = bf2f(scw[scoff(c, 40 + hp)]);
                    scw[scoff(c, hp)] = f2bf(sigm(g1[2][ct][r]) * fn);
                }
                if (quad == 0) {
                    #pragma unroll
                    for (int r = 0; r < 4; r++) {
                        int hp = 16 + r;
                        float fn = bf2f(scw[scoff(c, 40 + hp)]);
                        scw[scoff(c, hp)] = f2bf(sigm(g1[3][ct][r]) * fn);
                    }
                }
            }

            // 3d: hu = W5u_pad(32x32) @ rp
            f4 hu[2][2];
            hu[0][0] = (f4){0,0,0,0}; hu[0][1] = (f4){0,0,0,0};
            hu[1][0] = (f4){0,0,0,0}; hu[1][1] = (f4){0,0,0,0};
            #pragma unroll
            for (int ct = 0; ct < 2; ct++) {
                int c = ct * 16 + l16;
                int fb = quad ^ (c & 7);
                bf8 bfr = *(const bf8*)&scw[c * 64 + fb * 8];
                #pragma unroll
                for (int mt = 0; mt < 2; mt++) {
                    bf8 wf = *(const bf8*)(whu + ((size_t)(mt * 64) + lane) * 8);
                    hu[mt][ct] = MFMA(wf, bfr, hu[mt][ct]);
                }
            }

            // 3e: fn_new = (1-z)*fn + z*tanh(h_av + hu); write nodes + feats 0..19
            #pragma unroll
            for (int ct = 0; ct < 2; ct++) {
                int c = ct * 16 + l16;
                size_t nbase = ((size_t)(b0 + ct) * H_SZ) * N_SZ + nglob;
                #pragma unroll
                for (int r = 0; r < 4; r++) {
                    int hp = quad * 4 + r;
                    float fn = bf2f(scw[scoff(c, 40 + hp)]);
                    float z = sigm(g1[0][ct][r]);
                    float hpre = g1[4][ct][r] + hu[0][ct][r];
                    float hv = 2.f / (1.f + __expf(-2.f * hpre)) - 1.f;
                    u16 w = f2bf((1.f - z) * fn + z * hv);
                    nodes[nbase + (size_t)hp * N_SZ] = w;
                    scw[scoff(c, hp)] = w;
                }
                if (quad == 0) {
                    #pragma unroll
                    for (int r = 0; r < 4; r++) {
                        int hp = 16 + r;
                        float fn = bf2f(scw[scoff(c, 40 + hp)]);
                        float z = sigm(g1[1][ct][r]);
                        float hpre = g1[5][ct][r] + hu[1][ct][r];
                        float hv = 2.f / (1.f + __expf(-2.f * hpre)) - 1.f;
                        u16 w = f2bf((1.f - z) * fn + z * hv);
                        nodes[nbase + (size_t)hp * N_SZ] = w;
                        scw[scoff(c, hp)] = w;
                    }
                }
            }

            // 3f: og = Wo1_pad(32x32) @ fn_new
            f4 og[2][2];
            og[0][0] = (f4){0,0,0,0}; og[0][1] = (f4){0,0,0,0};
            og[1][0] = (f4){0,0,0,0}; og[1][1] = (f4){0,0,0,0};
            #pragma unroll
            for (int ct = 0; ct < 2; ct++) {
                int c = ct * 16 + l16;
                int fb = quad ^ (c & 7);
                bf8 bfr = *(const bf8*)&scw[c * 64 + fb * 8];
                #pragma unroll
                for (int mt = 0; mt < 2; mt++) {
                    bf8 wf = *(const bf8*)(wo1 + ((size_t)(mt * 64) + lane) * 8);
                    og[mt][ct] = MFMA(wf, bfr, og[mt][ct]);
                }
            }

            // 3g: out = og + xo, float4 stores
            #pragma unroll
            for (int ct = 0; ct < 2; ct++) {
                int bg = b0 + ct;
                size_t xob = ((size_t)bg * N_SZ + nglob) * H_SZ;
                size_t ob = (((size_t)t_step * B_SZ + bg) * N_SZ + nglob) * H_SZ;
                {
                    f4 v;
                    #pragma unroll
                    for (int r = 0; r < 4; r++) v[r] = og[0][ct][r] + bf2f(xo[xob + quad * 4 + r]);
                    *(f4*)(out + ob + quad * 4) = v;
                }
                if (quad == 0) {
                    f4 v;
                    #pragma unroll
                    for (int r = 0; r < 4; r++) v[r] = og[1][ct][r] + bf2f(xo[xob + 16 + r]);
                    *(f4*)(out + ob + 16) = v;
                }
            }
        }
    }
}

// ---------------- host ----------------
#define WS_NODES   0
#define WS_XO      41943040UL
#define WS_PAT     83886080UL
#define WS_PA      84410368UL
#define WS_WBIG    84934656UL
#define WS_WHU     84946944UL
#define WS_WO1     84948992UL
#define WS_NEEDED  84951040UL

extern "C" void kernel_launch(void* const* d_in, const int* in_sizes, int n_in,
                              void* d_out, int out_size, void* d_ws, size_t ws_size,
                              hipStream_t stream) {
    const float* x    = (const float*)d_in[0];
    const float* A    = (const float*)d_in[1];
    const float* W3w  = (const float*)d_in[2];
    const float* W3u  = (const float*)d_in[3];
    const float* W4w  = (const float*)d_in[4];
    const float* W4u  = (const float*)d_in[5];
    const float* W5w  = (const float*)d_in[6];
    const float* W5u  = (const float*)d_in[7];
    const float* Wout = (const float*)d_in[8];
    const float* bout = (const float*)d_in[9];
    float* out = (float*)d_out;

    if (ws_size < WS_NEEDED) {           // unambiguous failure signature
        ws_too_small<<<1, 1, 0, stream>>>(out);
        return;
    }
    char* ws = (char*)d_ws;
    u16* nodes = (u16*)(ws + WS_NODES);
    u16* xo    = (u16*)(ws + WS_XO);
    u16* pAT   = (u16*)(ws + WS_PAT);
    u16* pA    = (u16*)(ws + WS_PA);
    u16* wbig  = (u16*)(ws + WS_WBIG);
    u16* whu   = (u16*)(ws + WS_WHU);
    u16* wo1   = (u16*)(ws + WS_WO1);

    prep_nodes<<<B_SZ, 256, 0, stream>>>(x, nodes);
    prep_xo<<<(B_SZ * N_SZ) / 256, 256, 0, stream>>>(x, Wout, bout, xo);
    prep_afrag<<<128, 256, 0, stream>>>(A, pAT, pA);
    prep_wfrag<<<4, 256, 0, stream>>>(W3w, W3u, W4w, W4u, W5w, W5u, Wout, wbig, whu, wo1);

    for (int t = 0; t < T_STEPS; t++)
        step_kernel<<<B_SZ / 2, 512, 0, stream>>>(pAT, pA, wbig, whu, wo1, xo, nodes, out, t);
}

// Round 3
// 831.667 us; speedup vs baseline: 1.6962x; 1.6376x over previous
//
#include <hip/hip_runtime.h>
#include <stdint.h>

// Problem constants
#define B_SZ 2048
#define N_SZ 512
#define H_SZ 20
#define T_STEPS 3

typedef unsigned short u16;
typedef __attribute__((ext_vector_type(8))) short bf8;   // 8 bf16 (4 VGPRs)
typedef __attribute__((ext_vector_type(4))) float f4;    // MFMA 16x16 accumulator

#define MFMA(a, b, c) __builtin_amdgcn_mfma_f32_16x16x32_bf16((a), (b), (c), 0, 0, 0)

__device__ __forceinline__ u16 f2bf(float f) {
    union { float f; uint32_t u; } v; v.f = f;
    uint32_t u = v.u;
    u += 0x7FFFu + ((u >> 16) & 1u);   // RNE
    return (u16)(u >> 16);
}
__device__ __forceinline__ float bf2f(u16 h) {
    union { uint32_t u; float f; } v; v.u = ((uint32_t)h) << 16;
    return v.f;
}
// scratch2 addressing: [c (32 cols)][fblock^swizzle (8)][8], bf16 elements
__device__ __forceinline__ int scoff(int c, int f) {
    return c * 64 + (((f >> 3) ^ (c & 7)) << 3) + (f & 7);
}
__device__ __forceinline__ float sigm(float x) { return 1.f / (1.f + __expf(-x)); }

// ---------------- prep kernels ----------------

// x [B][N][H] f32 -> nodes [B][nt(32)][h(20)][nl(16)] bf16  (one block per batch)
// Tile-major layout: each (b, n-tile) slice is 640 B contiguous, so the step
// kernel's fn_new writes are line-coalesced (no partial-line RMW).
__global__ void prep_nodes(const float* __restrict__ x, u16* __restrict__ nodes) {
    __shared__ float xt[N_SZ * H_SZ];
    int b = blockIdx.x;
    const float* xb = x + (size_t)b * N_SZ * H_SZ;
    for (int i = threadIdx.x; i < N_SZ * H_SZ; i += 256) xt[i] = xb[i];
    __syncthreads();
    u16* nb = nodes + (size_t)b * (N_SZ * H_SZ);
    for (int i = threadIdx.x; i < N_SZ * H_SZ; i += 256) {
        // i = nt*320 + hp*16 + nl
        int nt = i / 320;
        int r  = i - nt * 320;
        int hp = r >> 4, nl = r & 15;
        int n = nt * 16 + nl;
        nb[i] = f2bf(xt[n * H_SZ + hp]);
    }
}

// xo [B][N][H] bf16 = x @ W_out[:,H:].T + b_out  (thread per (b,n))
__global__ void prep_xo(const float* __restrict__ x, const float* __restrict__ Wout,
                        const float* __restrict__ bout, u16* __restrict__ xo) {
    int i = blockIdx.x * 256 + threadIdx.x;      // (b*N+n)
    const float* xv = x + (size_t)i * H_SZ;
    float xl[H_SZ];
    #pragma unroll
    for (int h = 0; h < H_SZ; h++) xl[h] = xv[h];
    u16* o = xo + (size_t)i * H_SZ;
    for (int hp = 0; hp < H_SZ; hp++) {
        float s = bout[hp];
        const float* wr = Wout + hp * 2 * H_SZ + H_SZ;
        #pragma unroll
        for (int h = 0; h < H_SZ; h++) s += xl[h] * wr[h];
        o[hp] = f2bf(s);
    }
}

// A fragment tables: pAT[nt][kt][lane][8] = A[n][m] (B-op for agg_in),
//                    pA [nt][kt][lane][8] = A[m][n] (B-op for agg_out)
__global__ void prep_afrag(const float* __restrict__ A, u16* __restrict__ pAT,
                           u16* __restrict__ pA) {
    int idx = blockIdx.x * 256 + threadIdx.x;    // (nt*16 + kt)*64 + lane
    int lane = idx & 63;
    int kt = (idx >> 6) & 15;
    int nt = idx >> 10;
    int n = nt * 16 + (lane & 15);
    int k0 = kt * 32 + (lane >> 4) * 8;
    u16* d1 = pAT + (size_t)idx * 8;
    u16* d2 = pA + (size_t)idx * 8;
    #pragma unroll
    for (int j = 0; j < 8; j++) {
        int m = k0 + j;
        d1[j] = f2bf(A[(size_t)n * N_SZ + m]);
        d2[j] = f2bf(A[(size_t)m * N_SZ + n]);
    }
}

// Gate weight fragment tables.
// wbig: M=96 (rows 0-19 z | 32-51 r | 64-83 h-av; zero pad), K=64
//       (k 0-39: W*w over [agg_in,agg_out]; k 40-59: W*u over fn (zero for h); 60-63 zero)
// whu : M=32 K=32 : W5u zero-padded
// wo1 : M=32 K=32 : W_out[:, :H] zero-padded
__global__ void prep_wfrag(const float* __restrict__ W3w, const float* __restrict__ W3u,
                           const float* __restrict__ W4w, const float* __restrict__ W4u,
                           const float* __restrict__ W5w, const float* __restrict__ W5u,
                           const float* __restrict__ Wout,
                           u16* __restrict__ wbig, u16* __restrict__ whu, u16* __restrict__ wo1) {
    int t = blockIdx.x * 256 + threadIdx.x;      // 0..1023
    int lane = t & 63;
    int l16 = lane & 15, quad = lane >> 4;
    if (t < 768) {
        int kt = (t >> 6) & 1;
        int mt = t >> 7;
        int mrow = mt * 16 + l16;
        int g = mrow >> 5, lr = mrow & 31;
        u16* d = wbig + (size_t)t * 8;
        #pragma unroll
        for (int j = 0; j < 8; j++) {
            int k = kt * 32 + quad * 8 + j;
            float v = 0.f;
            if (lr < 20) {
                if (k < 40) {
                    const float* W = (g == 0) ? W3w : (g == 1) ? W4w : W5w;
                    v = W[lr * 40 + k];
                } else if (k < 60 && g < 2) {
                    const float* U = (g == 0) ? W3u : W4u;
                    v = U[lr * 20 + (k - 40)];
                }
            }
            d[j] = f2bf(v);
        }
    } else if (t < 896) {
        int tt = t - 768;
        int mrow = (tt >> 6) * 16 + l16;
        u16* d = whu + (size_t)tt * 8;
        #pragma unroll
        for (int j = 0; j < 8; j++) {
            int k = quad * 8 + j;
            d[j] = f2bf((mrow < 20 && k < 20) ? W5u[mrow * 20 + k] : 0.f);
        }
    } else {
        int tt = t - 896;
        int mrow = (tt >> 6) * 16 + l16;
        u16* d = wo1 + (size_t)tt * 8;
        #pragma unroll
        for (int j = 0; j < 8; j++) {
            int k = quad * 8 + j;
            d[j] = f2bf((mrow < 20 && k < 20) ? Wout[mrow * 40 + k] : 0.f);
        }
    }
}

__global__ void ws_too_small(float* out) { out[0] = 12345.0f; }

// ---------------- fused all-steps kernel ----------------
// One workgroup = 2 batches for ALL T steps. LDS: Xs[40 rows (b,h)][512 m]
// bf16 XOR-swizzled + per-wave scratch2 (32 cols x 64 feats, swizzled).
// Per step: stage nodes->Xs, barrier, compute (phase 2/3 identical to the
// 875us round-0 kernel), write fn_new to tile-major nodes (contiguous 640 B
// per (b,ntile) -> no partial-line RMW), barrier, restage.
// Phase 2 reads only the Xs snapshot, so in-step global writes never race.
__global__ __launch_bounds__(256, 2)
void step_kernel(const u16* __restrict__ pAT, const u16* __restrict__ pA,
                 const u16* __restrict__ wbig, const u16* __restrict__ whu,
                 const u16* __restrict__ wo1, const u16* __restrict__ xo,
                 u16* __restrict__ nodes, float* __restrict__ out)
{
    __shared__ __align__(16) u16 lds_all[40 * 512 + 4 * 2048];   // Xs | sc2, 57344 B
    u16* Xs = lds_all;
    int tid = threadIdx.x;
    int wv = tid >> 6, lane = tid & 63;
    int l16 = lane & 15, quad = lane >> 4;
    int b0 = blockIdx.x * 2;
    u16* scw = lds_all + 40 * 512 + wv * 2048;

    const u16* nb = nodes + (size_t)b0 * (N_SZ * H_SZ);   // 2 batches, tile-major

    #pragma unroll 1
    for (int t = 0; t < T_STEPS; t++) {
        // ---- phase 1: stage nodes[b0..b0+1] -> Xs (swizzled) ----
        // nodes layout flat: idx8*8 = bs*10240 + nt*320 + hp*16 + nl0
        #pragma unroll
        for (int i = 0; i < 10; i++) {
            int idx = i * 256 + tid;                 // 0..2559 uint4-groups
            uint4 v = *(const uint4*)(nb + (size_t)idx * 8);
            int bs = idx >= 1280 ? 1 : 0;
            int idxb = idx - bs * 1280;
            int nt = idxb / 40;                      // 40 groups per n-tile
            int r  = idxb - nt * 40;
            int hp = r >> 1;
            int half = r & 1;                        // nl0 = half*8
            int row = bs * 20 + hp;
            int mb = nt * 2 + half;                  // (nt*16+nl0)>>3
            *(uint4*)&Xs[row * 512 + ((mb ^ (row & 7)) << 3)] = v;
        }
        __syncthreads();
        // From here waves are fully independent (own n-tiles, own scratch).

        for (int p = 0; p < 4; p++) {
            int nt0 = wv * 8 + p * 2;

            // ---- phase 2: aggregation GEMM for an n-tile pair ----
            f4 acc[2][3][2];                    // [ntL][mt][agg]
            #pragma unroll
            for (int a0 = 0; a0 < 2; a0++)
                #pragma unroll
                for (int a1 = 0; a1 < 3; a1++)
                    #pragma unroll
                    for (int a2 = 0; a2 < 2; a2++)
                        acc[a0][a1][a2] = (f4){0.f, 0.f, 0.f, 0.f};

            for (int kt = 0; kt < 16; kt++) {
                bf8 af[3];
                #pragma unroll
                for (int mt = 0; mt < 3; mt++) {
                    int row = mt * 16 + l16;                   // rows 40-47 read junk; C rows ignored
                    int kb = (kt * 4 + quad) ^ (row & 7);
                    af[mt] = *(const bf8*)&Xs[row * 512 + kb * 8];
                }
                #pragma unroll
                for (int ntL = 0; ntL < 2; ntL++) {
                    size_t fo = ((size_t)((nt0 + ntL) * 16 + kt) * 64 + lane) * 8;
                    bf8 bi = *(const bf8*)(pAT + fo);
                    bf8 bo = *(const bf8*)(pA + fo);
                    #pragma unroll
                    for (int mt = 0; mt < 3; mt++) {
                        acc[ntL][mt][0] = MFMA(af[mt], bi, acc[ntL][mt][0]);
                        acc[ntL][mt][1] = MFMA(af[mt], bo, acc[ntL][mt][1]);
                    }
                }
            }

            // ---- phase 3: gates + update + output, per n-tile ----
            #pragma unroll
            for (int ntL = 0; ntL < 2; ntL++) {
                int nt = nt0 + ntL;
                int nglob = nt * 16 + l16;

                // 3a: agg C-tiles -> scratch2 feats 0..39 (f = agg*20+h, c = bsub*16+n_local)
                #pragma unroll
                for (int mt = 0; mt < 3; mt++) {
                    if (mt < 2 || quad < 2) {
                        int row0 = mt * 16 + quad * 4;          // 4-aligned; 20-boundary safe
                        int bs = (row0 >= 20) ? 1 : 0;
                        int h0 = row0 - bs * 20;
                        int c = bs * 16 + l16;
                        #pragma unroll
                        for (int r = 0; r < 4; r++) {
                            scw[scoff(c, h0 + r)]      = f2bf(acc[ntL][mt][0][r]);
                            scw[scoff(c, 20 + h0 + r)] = f2bf(acc[ntL][mt][1][r]);
                        }
                    }
                }
                // 3a2: fn -> feats 40..59 ; zero feats 60..63 (avoid NaN garbage into MFMA)
                {
                    int c = lane & 31;
                    int h0 = (lane >> 5) * 10;
                    int bs = c >> 4, nl = c & 15;
                    int m = nt * 16 + nl;
                    int mb = m >> 3, mo = m & 7;
                    #pragma unroll
                    for (int i = 0; i < 10; i++) {
                        int h = h0 + i;
                        int row = bs * 20 + h;
                        u16 v = Xs[row * 512 + ((mb ^ (row & 7)) << 3) + mo];
                        scw[scoff(c, 40 + h)] = v;
                    }
                    if (lane < 32) {
                        #pragma unroll
                        for (int f = 60; f < 64; f++) scw[scoff(c, f)] = 0;
                    }
                }

                // 3b: G1 = Wbig(96x64) @ scratch2(64x32): z|r|h_av pre-activations
                f4 g1[6][2];
                #pragma unroll
                for (int a0 = 0; a0 < 6; a0++) { g1[a0][0] = (f4){0,0,0,0}; g1[a0][1] = (f4){0,0,0,0}; }
                #pragma unroll
                for (int kt = 0; kt < 2; kt++) {
                    bf8 bfr[2];
                    #pragma unroll
                    for (int ct = 0; ct < 2; ct++) {
                        int c = ct * 16 + l16;
                        int fb = (kt * 4 + quad) ^ (c & 7);
                        bfr[ct] = *(const bf8*)&scw[c * 64 + fb * 8];
                    }
                    #pragma unroll
                    for (int mt = 0; mt < 6; mt++) {
                        bf8 wf = *(const bf8*)(wbig + ((size_t)(mt * 2 + kt) * 64 + lane) * 8);
                        g1[mt][0] = MFMA(wf, bfr[0], g1[mt][0]);
                        g1[mt][1] = MFMA(wf, bfr[1], g1[mt][1]);
                    }
                }

                // 3c: rp = sigmoid(r)*fn -> feats 0..19 (agg_in slots are dead)
                #pragma unroll
                for (int ct = 0; ct < 2; ct++) {
                    int c = ct * 16 + l16;
                    #pragma unroll
                    for (int r = 0; r < 4; r++) {
                        int hp = quad * 4 + r;
                        float fn = bf2f(scw[scoff(c, 40 + hp)]);
                        scw[scoff(c, hp)] = f2bf(sigm(g1[2][ct][r]) * fn);
                    }
                    if (quad == 0) {
                        #pragma unroll
                        for (int r = 0; r < 4; r++) {
                            int hp = 16 + r;
                            float fn = bf2f(scw[scoff(c, 40 + hp)]);
                            scw[scoff(c, hp)] = f2bf(sigm(g1[3][ct][r]) * fn);
                        }
                    }
                }

                // 3d: hu = W5u_pad(32x32) @ rp
                f4 hu[2][2];
                hu[0][0] = (f4){0,0,0,0}; hu[0][1] = (f4){0,0,0,0};
                hu[1][0] = (f4){0,0,0,0}; hu[1][1] = (f4){0,0,0,0};
                #pragma unroll
                for (int ct = 0; ct < 2; ct++) {
                    int c = ct * 16 + l16;
                    int fb = quad ^ (c & 7);
                    bf8 bfr = *(const bf8*)&scw[c * 64 + fb * 8];
                    #pragma unroll
                    for (int mt = 0; mt < 2; mt++) {
                        bf8 wf = *(const bf8*)(whu + ((size_t)(mt * 64) + lane) * 8);
                        hu[mt][ct] = MFMA(wf, bfr, hu[mt][ct]);
                    }
                }

                // 3e: fn_new = (1-z)*fn + z*tanh(h_av + hu); write nodes (tile-major,
                //     contiguous per (b,ntile)) + feats 0..19
                #pragma unroll
                for (int ct = 0; ct < 2; ct++) {
                    int c = ct * 16 + l16;
                    size_t nbase = ((size_t)(b0 + ct) * 32 + nt) * 320 + l16;
                    #pragma unroll
                    for (int r = 0; r < 4; r++) {
                        int hp = quad * 4 + r;
                        float fn = bf2f(scw[scoff(c, 40 + hp)]);
                        float z = sigm(g1[0][ct][r]);
                        float hpre = g1[4][ct][r] + hu[0][ct][r];
                        float hv = 2.f / (1.f + __expf(-2.f * hpre)) - 1.f;
                        u16 w = f2bf((1.f - z) * fn + z * hv);
                        nodes[nbase + (size_t)hp * 16] = w;
                        scw[scoff(c, hp)] = w;
                    }
                    if (quad == 0) {
                        #pragma unroll
                        for (int r = 0; r < 4; r++) {
                            int hp = 16 + r;
                            float fn = bf2f(scw[scoff(c, 40 + hp)]);
                            float z = sigm(g1[1][ct][r]);
                            float hpre = g1[5][ct][r] + hu[1][ct][r];
                            float hv = 2.f / (1.f + __expf(-2.f * hpre)) - 1.f;
                            u16 w = f2bf((1.f - z) * fn + z * hv);
                            nodes[nbase + (size_t)hp * 16] = w;
                            scw[scoff(c, hp)] = w;
                        }
                    }
                }

                // 3f: og = Wo1_pad(32x32) @ fn_new
                f4 og[2][2];
                og[0][0] = (f4){0,0,0,0}; og[0][1] = (f4){0,0,0,0};
                og[1][0] = (f4){0,0,0,0}; og[1][1] = (f4){0,0,0,0};
                #pragma unroll
                for (int ct = 0; ct < 2; ct++) {
                    int c = ct * 16 + l16;
                    int fb = quad ^ (c & 7);
                    bf8 bfr = *(const bf8*)&scw[c * 64 + fb * 8];
                    #pragma unroll
                    for (int mt = 0; mt < 2; mt++) {
                        bf8 wf = *(const bf8*)(wo1 + ((size_t)(mt * 64) + lane) * 8);
                        og[mt][ct] = MFMA(wf, bfr, og[mt][ct]);
                    }
                }

                // 3g: out = og + xo, float4 stores
                #pragma unroll
                for (int ct = 0; ct < 2; ct++) {
                    int bg = b0 + ct;
                    size_t xob = ((size_t)bg * N_SZ + nglob) * H_SZ;
                    size_t ob = (((size_t)t * B_SZ + bg) * N_SZ + nglob) * H_SZ;
                    {
                        f4 v;
                        #pragma unroll
                        for (int r = 0; r < 4; r++) v[r] = og[0][ct][r] + bf2f(xo[xob + quad * 4 + r]);
                        *(f4*)(out + ob + quad * 4) = v;
                    }
                    if (quad == 0) {
                        f4 v;
                        #pragma unroll
                        for (int r = 0; r < 4; r++) v[r] = og[1][ct][r] + bf2f(xo[xob + 16 + r]);
                        *(f4*)(out + ob + 16) = v;
                    }
                }
            }
        }
        // all waves must finish global nodes writes before anyone restages
        if (t < T_STEPS - 1) __syncthreads();
    }
}

// ---------------- host ----------------
#define WS_NODES   0
#define WS_XO      41943040UL
#define WS_PAT     83886080UL
#define WS_PA      84410368UL
#define WS_WBIG    84934656UL
#define WS_WHU     84946944UL
#define WS_WO1     84948992UL
#define WS_NEEDED  84951040UL

extern "C" void kernel_launch(void* const* d_in, const int* in_sizes, int n_in,
                              void* d_out, int out_size, void* d_ws, size_t ws_size,
                              hipStream_t stream) {
    const float* x    = (const float*)d_in[0];
    const float* A    = (const float*)d_in[1];
    const float* W3w  = (const float*)d_in[2];
    const float* W3u  = (const float*)d_in[3];
    const float* W4w  = (const float*)d_in[4];
    const float* W4u  = (const float*)d_in[5];
    const float* W5w  = (const float*)d_in[6];
    const float* W5u  = (const float*)d_in[7];
    const float* Wout = (const float*)d_in[8];
    const float* bout = (const float*)d_in[9];
    float* out = (float*)d_out;

    if (ws_size < WS_NEEDED) {           // unambiguous failure signature
        ws_too_small<<<1, 1, 0, stream>>>(out);
        return;
    }
    char* ws = (char*)d_ws;
    u16* nodes = (u16*)(ws + WS_NODES);
    u16* xo    = (u16*)(ws + WS_XO);
    u16* pAT   = (u16*)(ws + WS_PAT);
    u16* pA    = (u16*)(ws + WS_PA);
    u16* wbig  = (u16*)(ws + WS_WBIG);
    u16* whu   = (u16*)(ws + WS_WHU);
    u16* wo1   = (u16*)(ws + WS_WO1);

    prep_nodes<<<B_SZ, 256, 0, stream>>>(x, nodes);
    prep_xo<<<(B_SZ * N_SZ) / 256, 256, 0, stream>>>(x, Wout, bout, xo);
    prep_afrag<<<128, 256, 0, stream>>>(A, pAT, pA);
    prep_wfrag<<<4, 256, 0, stream>>>(W3w, W3u, W4w, W4u, W5w, W5u, Wout, wbig, whu, wo1);

    step_kernel<<<B_SZ / 2, 256, 0, stream>>>(pAT, pA, wbig, whu, wo1, xo, nodes, out);
}

// Round 4
// 774.100 us; speedup vs baseline: 1.8223x; 1.0744x over previous
//
#include <hip/hip_runtime.h>
#include <stdint.h>

// Problem constants
#define B_SZ 2048
#define N_SZ 512
#define H_SZ 20
#define T_STEPS 3

typedef unsigned short u16;
typedef __attribute__((ext_vector_type(8))) short bf8;   // 8 bf16 (4 VGPRs)
typedef __attribute__((ext_vector_type(4))) float f4;    // MFMA 16x16 accumulator

#define MFMA(a, b, c) __builtin_amdgcn_mfma_f32_16x16x32_bf16((a), (b), (c), 0, 0, 0)

// HW RNE conversion: compiler emits v_cvt_pk_bf16_f32 for (pairs of) casts.
__device__ __forceinline__ u16 f2bf(float f) {
    __bf16 h = (__bf16)f;
    union { __bf16 b; u16 u; } v; v.b = h;
    return v.u;
}
__device__ __forceinline__ float bf2f(u16 h) {
    union { uint32_t u; float f; } v; v.u = ((uint32_t)h) << 16;
    return v.f;
}
__device__ __forceinline__ uint32_t pk2(float a, float b) {
    return (uint32_t)f2bf(a) | ((uint32_t)f2bf(b) << 16);
}
__device__ __forceinline__ uint2 pack4(f4 v) {
    uint2 r; r.x = pk2(v[0], v[1]); r.y = pk2(v[2], v[3]); return r;
}
// scratch2 addressing: [c (32 cols)][fblock^swizzle (8)][8], bf16 elements
__device__ __forceinline__ int scoff(int c, int f) {
    return c * 64 + (((f >> 3) ^ (c & 7)) << 3) + (f & 7);
}
__device__ __forceinline__ float sigm(float x) { return 1.f / (1.f + __expf(-x)); }

// ---------------- prep kernels ----------------

// Fused prep: x [B][N][H] f32 read ONCE per batch ->
//   nodes [B][nt(32)][h(20)][nl(16)] bf16 (tile-major, uint4 stores)
//   xo    [B][N][H] bf16 = x @ W_out[:,H:].T + b_out (uint2 stores)
__global__ __launch_bounds__(256)
void prep_fused(const float* __restrict__ x, const float* __restrict__ Wout,
                const float* __restrict__ bout,
                u16* __restrict__ nodes, u16* __restrict__ xo) {
    __shared__ float xt[N_SZ * H_SZ];      // 40960 B
    __shared__ float wo2[H_SZ * H_SZ];     // W_out[:, 20:40]
    __shared__ float bo[H_SZ];
    int tid = threadIdx.x;
    int b = blockIdx.x;
    const float4* xb4 = (const float4*)(x + (size_t)b * (N_SZ * H_SZ));
    #pragma unroll
    for (int i = 0; i < 10; i++) ((float4*)xt)[i * 256 + tid] = xb4[i * 256 + tid];
    for (int i = tid; i < H_SZ * H_SZ; i += 256)
        wo2[i] = Wout[(i / H_SZ) * 2 * H_SZ + H_SZ + (i % H_SZ)];
    if (tid < H_SZ) bo[tid] = bout[tid];
    __syncthreads();

    // nodes: 1280 uint4 groups; g = nt*40 + hp*2 + half, nl0 = half*8
    u16* nb = nodes + (size_t)b * (N_SZ * H_SZ);
    #pragma unroll
    for (int g0 = 0; g0 < 5; g0++) {
        int g = g0 * 256 + tid;
        int nt = g / 40, r = g - nt * 40;
        int hp = r >> 1, nl0 = (r & 1) * 8;
        union { uint4 v; u16 s[8]; } u;
        #pragma unroll
        for (int j = 0; j < 8; j++) u.s[j] = f2bf(xt[(nt * 16 + nl0 + j) * H_SZ + hp]);
        *(uint4*)&nb[(size_t)g * 8] = u.v;
    }

    // xo: one n per thread (x2), packed uint2 stores (40 B/row -> 8B aligned)
    u16* ob = xo + (size_t)b * (N_SZ * H_SZ);
    #pragma unroll
    for (int n0 = 0; n0 < 2; n0++) {
        int n = n0 * 256 + tid;
        float xl[H_SZ];
        #pragma unroll
        for (int h = 0; h < H_SZ; h++) xl[h] = xt[n * H_SZ + h];
        #pragma unroll
        for (int q = 0; q < 5; q++) {
            float s[4];
            #pragma unroll
            for (int k = 0; k < 4; k++) {
                int hp = q * 4 + k;
                float acc = bo[hp];
                #pragma unroll
                for (int h = 0; h < H_SZ; h++) acc += xl[h] * wo2[hp * H_SZ + h];
                s[k] = acc;
            }
            uint2 v; v.x = pk2(s[0], s[1]); v.y = pk2(s[2], s[3]);
            *(uint2*)&ob[(size_t)n * H_SZ + q * 4] = v;
        }
    }
}

// A fragment tables: pAT[nt][kt][lane][8] = A[n][m] (B-op for agg_in),
//                    pA [nt][kt][lane][8] = A[m][n] (B-op for agg_out)
__global__ void prep_afrag(const float* __restrict__ A, u16* __restrict__ pAT,
                           u16* __restrict__ pA) {
    int idx = blockIdx.x * 256 + threadIdx.x;    // (nt*16 + kt)*64 + lane
    int lane = idx & 63;
    int kt = (idx >> 6) & 15;
    int nt = idx >> 10;
    int n = nt * 16 + (lane & 15);
    int k0 = kt * 32 + (lane >> 4) * 8;
    u16* d1 = pAT + (size_t)idx * 8;
    u16* d2 = pA + (size_t)idx * 8;
    #pragma unroll
    for (int j = 0; j < 8; j++) {
        int m = k0 + j;
        d1[j] = f2bf(A[(size_t)n * N_SZ + m]);
        d2[j] = f2bf(A[(size_t)m * N_SZ + n]);
    }
}

// Gate weight fragment tables.
// wbig: M=96 (rows 0-19 z | 32-51 r | 64-83 h-av; zero pad), K=64
//       (k 0-39: W*w over [agg_in,agg_out]; k 40-59: W*u over fn (zero for h); 60-63 zero)
// whu : M=32 K=32 : W5u zero-padded
// wo1 : M=32 K=32 : W_out[:, :H] zero-padded
__global__ void prep_wfrag(const float* __restrict__ W3w, const float* __restrict__ W3u,
                           const float* __restrict__ W4w, const float* __restrict__ W4u,
                           const float* __restrict__ W5w, const float* __restrict__ W5u,
                           const float* __restrict__ Wout,
                           u16* __restrict__ wbig, u16* __restrict__ whu, u16* __restrict__ wo1) {
    int t = blockIdx.x * 256 + threadIdx.x;      // 0..1023
    int lane = t & 63;
    int l16 = lane & 15, quad = lane >> 4;
    if (t < 768) {
        int kt = (t >> 6) & 1;
        int mt = t >> 7;
        int mrow = mt * 16 + l16;
        int g = mrow >> 5, lr = mrow & 31;
        u16* d = wbig + (size_t)t * 8;
        #pragma unroll
        for (int j = 0; j < 8; j++) {
            int k = kt * 32 + quad * 8 + j;
            float v = 0.f;
            if (lr < 20) {
                if (k < 40) {
                    const float* W = (g == 0) ? W3w : (g == 1) ? W4w : W5w;
                    v = W[lr * 40 + k];
                } else if (k < 60 && g < 2) {
                    const float* U = (g == 0) ? W3u : W4u;
                    v = U[lr * 20 + (k - 40)];
                }
            }
            d[j] = f2bf(v);
        }
    } else if (t < 896) {
        int tt = t - 768;
        int mrow = (tt >> 6) * 16 + l16;
        u16* d = whu + (size_t)tt * 8;
        #pragma unroll
        for (int j = 0; j < 8; j++) {
            int k = quad * 8 + j;
            d[j] = f2bf((mrow < 20 && k < 20) ? W5u[mrow * 20 + k] : 0.f);
        }
    } else {
        int tt = t - 896;
        int mrow = (tt >> 6) * 16 + l16;
        u16* d = wo1 + (size_t)tt * 8;
        #pragma unroll
        for (int j = 0; j < 8; j++) {
            int k = quad * 8 + j;
            d[j] = f2bf((mrow < 20 && k < 20) ? Wout[mrow * 40 + k] : 0.f);
        }
    }
}

__global__ void ws_too_small(float* out) { out[0] = 12345.0f; }

// ---------------- fused all-steps kernel ----------------
// One workgroup = 2 batches for ALL T steps. Structure identical to the
// round-3 winner; phase-3 LDS traffic packed to b64 and conversions done
// in HW (v_cvt_pk_bf16_f32).
__global__ __launch_bounds__(256, 2)
void step_kernel(const u16* __restrict__ pAT, const u16* __restrict__ pA,
                 const u16* __restrict__ wbig, const u16* __restrict__ whu,
                 const u16* __restrict__ wo1, const u16* __restrict__ xo,
                 u16* __restrict__ nodes, float* __restrict__ out)
{
    __shared__ __align__(16) u16 lds_all[40 * 512 + 4 * 2048];   // Xs | sc2, 57344 B
    u16* Xs = lds_all;
    int tid = threadIdx.x;
    int wv = tid >> 6, lane = tid & 63;
    int l16 = lane & 15, quad = lane >> 4;
    int b0 = blockIdx.x * 2;
    u16* scw = lds_all + 40 * 512 + wv * 2048;

    const u16* nb = nodes + (size_t)b0 * (N_SZ * H_SZ);   // 2 batches, tile-major

    #pragma unroll 1
    for (int t = 0; t < T_STEPS; t++) {
        // ---- phase 1: stage nodes[b0..b0+1] -> Xs (swizzled) ----
        #pragma unroll
        for (int i = 0; i < 10; i++) {
            int idx = i * 256 + tid;                 // 0..2559 uint4-groups
            uint4 v = *(const uint4*)(nb + (size_t)idx * 8);
            int bs = idx >= 1280 ? 1 : 0;
            int idxb = idx - bs * 1280;
            int nt = idxb / 40;                      // 40 groups per n-tile
            int r  = idxb - nt * 40;
            int hp = r >> 1;
            int half = r & 1;                        // nl0 = half*8
            int row = bs * 20 + hp;
            int mb = nt * 2 + half;                  // (nt*16+nl0)>>3
            *(uint4*)&Xs[row * 512 + ((mb ^ (row & 7)) << 3)] = v;
        }
        __syncthreads();
        // From here waves are fully independent (own n-tiles, own scratch).

        for (int p = 0; p < 4; p++) {
            int nt0 = wv * 8 + p * 2;

            // ---- phase 2: aggregation GEMM for an n-tile pair ----
            f4 acc[2][3][2];                    // [ntL][mt][agg]
            #pragma unroll
            for (int a0 = 0; a0 < 2; a0++)
                #pragma unroll
                for (int a1 = 0; a1 < 3; a1++)
                    #pragma unroll
                    for (int a2 = 0; a2 < 2; a2++)
                        acc[a0][a1][a2] = (f4){0.f, 0.f, 0.f, 0.f};

            for (int kt = 0; kt < 16; kt++) {
                bf8 af[3];
                #pragma unroll
                for (int mt = 0; mt < 3; mt++) {
                    int row = mt * 16 + l16;                   // rows 40-47 read junk; C rows ignored
                    int kb = (kt * 4 + quad) ^ (row & 7);
                    af[mt] = *(const bf8*)&Xs[row * 512 + kb * 8];
                }
                #pragma unroll
                for (int ntL = 0; ntL < 2; ntL++) {
                    size_t fo = ((size_t)((nt0 + ntL) * 16 + kt) * 64 + lane) * 8;
                    bf8 bi = *(const bf8*)(pAT + fo);
                    bf8 bo = *(const bf8*)(pA + fo);
                    #pragma unroll
                    for (int mt = 0; mt < 3; mt++) {
                        acc[ntL][mt][0] = MFMA(af[mt], bi, acc[ntL][mt][0]);
                        acc[ntL][mt][1] = MFMA(af[mt], bo, acc[ntL][mt][1]);
                    }
                }
            }

            // ---- phase 3: gates + update + output, per n-tile ----
            #pragma unroll
            for (int ntL = 0; ntL < 2; ntL++) {
                int nt = nt0 + ntL;
                int nglob = nt * 16 + l16;

                // 3a: agg C-tiles -> scratch feats 0..39, packed uint2
                //     (4-run of feats always within one swizzle block, 8B aligned)
                #pragma unroll
                for (int mt = 0; mt < 3; mt++) {
                    if (mt < 2 || quad < 2) {
                        int row0 = mt * 16 + quad * 4;          // 4-aligned; 20-boundary safe
                        int bs = (row0 >= 20) ? 1 : 0;
                        int h0 = row0 - bs * 20;
                        int c = bs * 16 + l16;
                        *(uint2*)&scw[scoff(c, h0)]      = pack4(acc[ntL][mt][0]);
                        *(uint2*)&scw[scoff(c, 20 + h0)] = pack4(acc[ntL][mt][1]);
                    }
                }
                // 3a2: fn -> feats 40..59 (packed writes); zero feats 60..63
                {
                    int c = lane & 31;
                    int h0 = (lane >> 5) * 10;
                    int bs = c >> 4, nl = c & 15;
                    int m = nt * 16 + nl;
                    int mb = m >> 3, mo = m & 7;
                    u16 fnv[10];
                    #pragma unroll
                    for (int i = 0; i < 10; i++) {
                        int row = bs * 20 + h0 + i;
                        fnv[i] = Xs[row * 512 + ((mb ^ (row & 7)) << 3) + mo];
                    }
                    if (h0 == 0) {          // feats 40..49
                        uint2 a; a.x = fnv[0] | (fnv[1] << 16); a.y = fnv[2] | (fnv[3] << 16);
                        *(uint2*)&scw[scoff(c, 40)] = a;
                        uint2 b2; b2.x = fnv[4] | (fnv[5] << 16); b2.y = fnv[6] | (fnv[7] << 16);
                        *(uint2*)&scw[scoff(c, 44)] = b2;
                        *(uint32_t*)&scw[scoff(c, 48)] = (uint32_t)fnv[8] | ((uint32_t)fnv[9] << 16);
                    } else {                // feats 50..59 + zero 60..63
                        *(uint32_t*)&scw[scoff(c, 50)] = (uint32_t)fnv[0] | ((uint32_t)fnv[1] << 16);
                        uint2 a; a.x = fnv[2] | (fnv[3] << 16); a.y = fnv[4] | (fnv[5] << 16);
                        *(uint2*)&scw[scoff(c, 52)] = a;
                        uint2 b2; b2.x = fnv[6] | (fnv[7] << 16); b2.y = fnv[8] | (fnv[9] << 16);
                        *(uint2*)&scw[scoff(c, 56)] = b2;
                        uint2 z; z.x = 0u; z.y = 0u;
                        *(uint2*)&scw[scoff(c, 60)] = z;
                    }
                }

                // 3b: G1 = Wbig(96x64) @ scratch2(64x32): z|r|h_av pre-activations
                f4 g1[6][2];
                #pragma unroll
                for (int a0 = 0; a0 < 6; a0++) { g1[a0][0] = (f4){0,0,0,0}; g1[a0][1] = (f4){0,0,0,0}; }
                #pragma unroll
                for (int kt = 0; kt < 2; kt++) {
                    bf8 bfr[2];
                    #pragma unroll
                    for (int ct = 0; ct < 2; ct++) {
                        int c = ct * 16 + l16;
                        int fb = (kt * 4 + quad) ^ (c & 7);
                        bfr[ct] = *(const bf8*)&scw[c * 64 + fb * 8];
                    }
                    #pragma unroll
                    for (int mt = 0; mt < 6; mt++) {
                        bf8 wf = *(const bf8*)(wbig + ((size_t)(mt * 2 + kt) * 64 + lane) * 8);
                        g1[mt][0] = MFMA(wf, bfr[0], g1[mt][0]);
                        g1[mt][1] = MFMA(wf, bfr[1], g1[mt][1]);
                    }
                }

                // 3c: rp = sigmoid(r)*fn -> feats 0..19 (packed); keep fn in regs
                float fnr[2][4], fnr2[2][4];
                #pragma unroll
                for (int ct = 0; ct < 2; ct++) {
                    int c = ct * 16 + l16;
                    uint2 fl = *(const uint2*)&scw[scoff(c, 40 + quad * 4)];
                    fnr[ct][0] = bf2f((u16)fl.x);  fnr[ct][1] = bf2f((u16)(fl.x >> 16));
                    fnr[ct][2] = bf2f((u16)fl.y);  fnr[ct][3] = bf2f((u16)(fl.y >> 16));
                    uint2 rp;
                    rp.x = pk2(sigm(g1[2][ct][0]) * fnr[ct][0], sigm(g1[2][ct][1]) * fnr[ct][1]);
                    rp.y = pk2(sigm(g1[2][ct][2]) * fnr[ct][2], sigm(g1[2][ct][3]) * fnr[ct][3]);
                    *(uint2*)&scw[scoff(c, quad * 4)] = rp;
                    if (quad == 0) {
                        uint2 fl2 = *(const uint2*)&scw[scoff(c, 56)];
                        fnr2[ct][0] = bf2f((u16)fl2.x);  fnr2[ct][1] = bf2f((u16)(fl2.x >> 16));
                        fnr2[ct][2] = bf2f((u16)fl2.y);  fnr2[ct][3] = bf2f((u16)(fl2.y >> 16));
                        uint2 rp2;
                        rp2.x = pk2(sigm(g1[3][ct][0]) * fnr2[ct][0], sigm(g1[3][ct][1]) * fnr2[ct][1]);
                        rp2.y = pk2(sigm(g1[3][ct][2]) * fnr2[ct][2], sigm(g1[3][ct][3]) * fnr2[ct][3]);
                        *(uint2*)&scw[scoff(c, 16)] = rp2;
                    }
                }

                // 3d: hu = W5u_pad(32x32) @ rp
                f4 hu[2][2];
                hu[0][0] = (f4){0,0,0,0}; hu[0][1] = (f4){0,0,0,0};
                hu[1][0] = (f4){0,0,0,0}; hu[1][1] = (f4){0,0,0,0};
                #pragma unroll
                for (int ct = 0; ct < 2; ct++) {
                    int c = ct * 16 + l16;
                    int fb = quad ^ (c & 7);
                    bf8 bfr = *(const bf8*)&scw[c * 64 + fb * 8];
                    #pragma unroll
                    for (int mt = 0; mt < 2; mt++) {
                        bf8 wf = *(const bf8*)(whu + ((size_t)(mt * 64) + lane) * 8);
                        hu[mt][ct] = MFMA(wf, bfr, hu[mt][ct]);
                    }
                }

                // 3e: fn_new = (1-z)*fn + z*tanh(h_av + hu); packed scw write,
                //     scalar global stores (tile-major: full 640B region per (b,nt))
                #pragma unroll
                for (int ct = 0; ct < 2; ct++) {
                    int c = ct * 16 + l16;
                    size_t nbase = ((size_t)(b0 + ct) * 32 + nt) * 320 + l16;
                    float w4[4];
                    #pragma unroll
                    for (int r = 0; r < 4; r++) {
                        float z = sigm(g1[0][ct][r]);
                        float hpre = g1[4][ct][r] + hu[0][ct][r];
                        float hv = 2.f / (1.f + __expf(-2.f * hpre)) - 1.f;
                        w4[r] = (1.f - z) * fnr[ct][r] + z * hv;
                    }
                    uint2 wp; wp.x = pk2(w4[0], w4[1]); wp.y = pk2(w4[2], w4[3]);
                    *(uint2*)&scw[scoff(c, quad * 4)] = wp;
                    nodes[nbase + (size_t)(quad * 4 + 0) * 16] = (u16)wp.x;
                    nodes[nbase + (size_t)(quad * 4 + 1) * 16] = (u16)(wp.x >> 16);
                    nodes[nbase + (size_t)(quad * 4 + 2) * 16] = (u16)wp.y;
                    nodes[nbase + (size_t)(quad * 4 + 3) * 16] = (u16)(wp.y >> 16);
                    if (quad == 0) {
                        float w42[4];
                        #pragma unroll
                        for (int r = 0; r < 4; r++) {
                            float z = sigm(g1[1][ct][r]);
                            float hpre = g1[5][ct][r] + hu[1][ct][r];
                            float hv = 2.f / (1.f + __expf(-2.f * hpre)) - 1.f;
                            w42[r] = (1.f - z) * fnr2[ct][r] + z * hv;
                        }
                        uint2 wp2; wp2.x = pk2(w42[0], w42[1]); wp2.y = pk2(w42[2], w42[3]);
                        *(uint2*)&scw[scoff(c, 16)] = wp2;
                        nodes[nbase + (size_t)16 * 16] = (u16)wp2.x;
                        nodes[nbase + (size_t)17 * 16] = (u16)(wp2.x >> 16);
                        nodes[nbase + (size_t)18 * 16] = (u16)wp2.y;
                        nodes[nbase + (size_t)19 * 16] = (u16)(wp2.y >> 16);
                    }
                }

                // 3f: og = Wo1_pad(32x32) @ fn_new
                f4 og[2][2];
                og[0][0] = (f4){0,0,0,0}; og[0][1] = (f4){0,0,0,0};
                og[1][0] = (f4){0,0,0,0}; og[1][1] = (f4){0,0,0,0};
                #pragma unroll
                for (int ct = 0; ct < 2; ct++) {
                    int c = ct * 16 + l16;
                    int fb = quad ^ (c & 7);
                    bf8 bfr = *(const bf8*)&scw[c * 64 + fb * 8];
                    #pragma unroll
                    for (int mt = 0; mt < 2; mt++) {
                        bf8 wf = *(const bf8*)(wo1 + ((size_t)(mt * 64) + lane) * 8);
                        og[mt][ct] = MFMA(wf, bfr, og[mt][ct]);
                    }
                }

                // 3g: out = og + xo, float4 stores
                #pragma unroll
                for (int ct = 0; ct < 2; ct++) {
                    int bg = b0 + ct;
                    size_t xob = ((size_t)bg * N_SZ + nglob) * H_SZ;
                    size_t ob = (((size_t)t * B_SZ + bg) * N_SZ + nglob) * H_SZ;
                    {
                        uint2 xp = *(const uint2*)(xo + xob + quad * 4);
                        f4 v;
                        v[0] = og[0][ct][0] + bf2f((u16)xp.x);
                        v[1] = og[0][ct][1] + bf2f((u16)(xp.x >> 16));
                        v[2] = og[0][ct][2] + bf2f((u16)xp.y);
                        v[3] = og[0][ct][3] + bf2f((u16)(xp.y >> 16));
                        *(f4*)(out + ob + quad * 4) = v;
                    }
                    if (quad == 0) {
                        uint2 xp = *(const uint2*)(xo + xob + 16);
                        f4 v;
                        v[0] = og[1][ct][0] + bf2f((u16)xp.x);
                        v[1] = og[1][ct][1] + bf2f((u16)(xp.x >> 16));
                        v[2] = og[1][ct][2] + bf2f((u16)xp.y);
                        v[3] = og[1][ct][3] + bf2f((u16)(xp.y >> 16));
                        *(f4*)(out + ob + 16) = v;
                    }
                }
            }
        }
        // all waves must finish global nodes writes before anyone restages
        if (t < T_STEPS - 1) __syncthreads();
    }
}

// ---------------- host ----------------
#define WS_NODES   0
#define WS_XO      41943040UL
#define WS_PAT     83886080UL
#define WS_PA      84410368UL
#define WS_WBIG    84934656UL
#define WS_WHU     84946944UL
#define WS_WO1     84948992UL
#define WS_NEEDED  84951040UL

extern "C" void kernel_launch(void* const* d_in, const int* in_sizes, int n_in,
                              void* d_out, int out_size, void* d_ws, size_t ws_size,
                              hipStream_t stream) {
    const float* x    = (const float*)d_in[0];
    const float* A    = (const float*)d_in[1];
    const float* W3w  = (const float*)d_in[2];
    const float* W3u  = (const float*)d_in[3];
    const float* W4w  = (const float*)d_in[4];
    const float* W4u  = (const float*)d_in[5];
    const float* W5w  = (const float*)d_in[6];
    const float* W5u  = (const float*)d_in[7];
    const float* Wout = (const float*)d_in[8];
    const float* bout = (const float*)d_in[9];
    float* out = (float*)d_out;

    if (ws_size < WS_NEEDED) {           // unambiguous failure signature
        ws_too_small<<<1, 1, 0, stream>>>(out);
        return;
    }
    char* ws = (char*)d_ws;
    u16* nodes = (u16*)(ws + WS_NODES);
    u16* xo    = (u16*)(ws + WS_XO);
    u16* pAT   = (u16*)(ws + WS_PAT);
    u16* pA    = (u16*)(ws + WS_PA);
    u16* wbig  = (u16*)(ws + WS_WBIG);
    u16* whu   = (u16*)(ws + WS_WHU);
    u16* wo1   = (u16*)(ws + WS_WO1);

    prep_fused<<<B_SZ, 256, 0, stream>>>(x, Wout, bout, nodes, xo);
    prep_afrag<<<128, 256, 0, stream>>>(A, pAT, pA);
    prep_wfrag<<<4, 256, 0, stream>>>(W3w, W3u, W4w, W4u, W5w, W5u, Wout, wbig, whu, wo1);

    step_kernel<<<B_SZ / 2, 256, 0, stream>>>(pAT, pA, wbig, whu, wo1, xo, nodes, out);
}